// Round 1
// baseline (68.724 us; speedup 1.0000x reference)
//
#include <hip/hip_runtime.h>

// ExpertMLP: h = sum_e coef[b,e] * (x @ w1[e]) + coef@b1 ; BN(batch) ; ELU ;
//            out = sum_e coef[b,e] * (h1 @ w2[e]) + coef@b2
// B=1024, E=8, IN=HID=OUT=512. All fp32 in/out; compute in bf16 MFMA + f32 acc.

typedef short bf16x8 __attribute__((ext_vector_type(8)));
typedef float f32x4 __attribute__((ext_vector_type(4)));
typedef unsigned short u16;
typedef u16 u16x4 __attribute__((ext_vector_type(4)));

__device__ __forceinline__ u16 f2bf(float f) {
  union { float f; unsigned u; } v; v.f = f;
  return (u16)((v.u + 0x7FFFu + ((v.u >> 16) & 1u)) >> 16);  // RNE
}

#define AS_G(p) ((const __attribute__((address_space(1))) void*)(p))
#define AS_L(p) ((__attribute__((address_space(3))) void*)(p))

// ---------------- prep: x -> bf16 ; w1,w2 -> transposed bf16 [e][n][k] -------
__global__ __launch_bounds__(256) void prep_kernel(
    const float* __restrict__ x, const float* __restrict__ w1,
    const float* __restrict__ w2, u16* __restrict__ xb,
    u16* __restrict__ w1t, u16* __restrict__ w2t)
{
  int bid = blockIdx.x, t = threadIdx.x;
  __shared__ float ld[64][65];   // padded to break bank conflicts on col reads
  if (bid < 128) {               // convert x: 128*256*16 = 524288 elems
    int p = (bid * 256 + t) * 16;
    #pragma unroll
    for (int i = 0; i < 4; ++i) {
      f32x4 v = *(const f32x4*)(x + p + i * 4);
      u16x4 o;
      o.x = f2bf(v.x); o.y = f2bf(v.y); o.z = f2bf(v.z); o.w = f2bf(v.w);
      *(u16x4*)(xb + p + i * 4) = o;
    }
    return;
  }
  int b2 = bid - 128;                        // 0..1023: 2 weights * 8 e * 64 tiles
  const float* src = (b2 >> 9) ? w2 : w1;
  u16* dst = (b2 >> 9) ? w2t : w1t;
  int rem = b2 & 511;
  int e = rem >> 6, tl = rem & 63;
  int kt = tl >> 3, nt = tl & 7;             // 64x64 tile at (kt,nt)
  #pragma unroll
  for (int j = 0; j < 4; ++j) {              // read [k][n] coalesced
    int kr = j * 16 + (t >> 4), nc = (t & 15) * 4;
    f32x4 v = *(const f32x4*)(src + (size_t)((e * 512 + kt * 64 + kr)) * 512 + nt * 64 + nc);
    ld[kr][nc] = v.x; ld[kr][nc + 1] = v.y; ld[kr][nc + 2] = v.z; ld[kr][nc + 3] = v.w;
  }
  __syncthreads();
  #pragma unroll
  for (int j = 0; j < 4; ++j) {              // write [n][k] coalesced, bf16
    int nr = j * 16 + (t >> 4), kc = (t & 15) * 4;
    u16x4 o;
    o.x = f2bf(ld[kc][nr]);     o.y = f2bf(ld[kc + 1][nr]);
    o.z = f2bf(ld[kc + 2][nr]); o.w = f2bf(ld[kc + 3][nr]);
    *(u16x4*)(dst + (size_t)((e * 512 + nt * 64 + nr)) * 512 + kt * 64 + kc) = o;
  }
}

// ---------------- per-expert GEMM: P[e] = A @ W[e]  (A:[1024][512] bf16,
//                  Wt:[8][512][512] bf16 stored [e][n][k]) ------------------
__global__ __launch_bounds__(256) void gemm_expert(
    const u16* __restrict__ A, const u16* __restrict__ Wt,
    float* __restrict__ P)
{
  // XCD swizzle: all 64 blocks of one expert land on one XCD (W panel L2-hot)
  int bid = (blockIdx.x & 7) * 64 + (blockIdx.x >> 3);   // 512 % 8 == 0, bijective
  int nt = bid & 7, mt = (bid >> 3) & 7, e = bid >> 6;
  int t = threadIdx.x, l = t & 63, w = t >> 6;
  int wm = w >> 1, wn = w & 1;                 // wave tile 64x32 of 128x64 block
  __shared__ alignas(16) u16 As[128 * 64];     // 16 KB, [row][k] linear
  __shared__ alignas(16) u16 Bs[64 * 64];      //  8 KB, [n][k] linear
  f32x4 acc[4][2] = {};
  const u16* Ag = A + (size_t)(mt * 128) * 512;
  const u16* Bg = Wt + (size_t)(e * 512 + nt * 64) * 512;
  int lr = l >> 3, lc = l & 7;                 // lane -> (row-in-8, 16B chunk)

  for (int kt = 0; kt < 8; ++kt) {
    int k0 = kt * 64;
    #pragma unroll
    for (int j = 0; j < 4; ++j) {              // stage A tile 128x64
      int row = j * 32 + w * 8;
      __builtin_amdgcn_global_load_lds(AS_G(Ag + (size_t)(row + lr) * 512 + k0 + lc * 8),
                                       AS_L(&As[row * 64]), 16, 0, 0);
    }
    #pragma unroll
    for (int j = 0; j < 2; ++j) {              // stage B tile 64x64
      int row = j * 32 + w * 8;
      __builtin_amdgcn_global_load_lds(AS_G(Bg + (size_t)(row + lr) * 512 + k0 + lc * 8),
                                       AS_L(&Bs[row * 64]), 16, 0, 0);
    }
    __syncthreads();                           // drains vmcnt before reads
    #pragma unroll
    for (int kk = 0; kk < 2; ++kk) {
      bf16x8 a[4], b[2];
      int ko = kk * 32 + (l >> 4) * 8;         // A/B frag: row=lane&15, k=8*(lane>>4)
      #pragma unroll
      for (int m = 0; m < 4; ++m)
        a[m] = *(const bf16x8*)&As[(wm * 64 + m * 16 + (l & 15)) * 64 + ko];
      #pragma unroll
      for (int n = 0; n < 2; ++n)
        b[n] = *(const bf16x8*)&Bs[(wn * 32 + n * 16 + (l & 15)) * 64 + ko];
      #pragma unroll
      for (int m = 0; m < 4; ++m)
        #pragma unroll
        for (int n = 0; n < 2; ++n)
          acc[m][n] = __builtin_amdgcn_mfma_f32_16x16x32_bf16(a[m], b[n], acc[m][n], 0, 0, 0);
    }
    __syncthreads();                           // LDS reads done before restage
  }
  // epilogue: C/D layout col=lane&15, row=(lane>>4)*4+reg (guide-verified)
  float* Pe = P + (size_t)((e << 10) + mt * 128 + wm * 64) * 512 + nt * 64 + wn * 32;
  #pragma unroll
  for (int m = 0; m < 4; ++m)
    #pragma unroll
    for (int n = 0; n < 2; ++n) {
      int col = n * 16 + (l & 15);
      int rbase = m * 16 + (l >> 4) * 4;
      #pragma unroll
      for (int r = 0; r < 4; ++r)
        Pe[(size_t)(rbase + r) * 512 + col] = acc[m][n][r];
    }
}

// ---------------- blend-reduce: out = sum_e coef*(P[e]+bias[e]); opt BN stats --
template <int STATS>
__global__ __launch_bounds__(256) void blend_kernel(
    const float* __restrict__ P, const float* __restrict__ coef,
    const float* __restrict__ bias, float* __restrict__ out,
    float* __restrict__ sSum, float* __restrict__ sSq)
{
  int bid = blockIdx.x;                      // 128 blocks: 64 row-blks x 2 col-blks
  int mblk = bid >> 1, cblk = bid & 1;
  int t = threadIdx.x, w = t >> 6, cg = t & 63;
  int col = cblk * 256 + cg * 4;
  f32x4 ssum = {0, 0, 0, 0}, ssq = {0, 0, 0, 0};
  #pragma unroll
  for (int rj = 0; rj < 4; ++rj) {
    int row = mblk * 16 + rj * 4 + w;
    const float* cr = coef + row * 8;
    f32x4 acc = {0, 0, 0, 0};
    #pragma unroll
    for (int e = 0; e < 8; ++e) {
      float c = cr[e];
      f32x4 p = *(const f32x4*)(P + (size_t)((e << 10) + row) * 512 + col);
      f32x4 bb = *(const f32x4*)(bias + e * 512 + col);
      acc += c * (p + bb);
    }
    *(f32x4*)(out + (size_t)row * 512 + col) = acc;
    if constexpr (STATS) { ssum += acc; ssq += acc * acc; }
  }
  if constexpr (STATS) {
    __shared__ f32x4 red[2][4][64];
    red[0][w][cg] = ssum; red[1][w][cg] = ssq;
    __syncthreads();
    if (w == 0) {
      #pragma unroll
      for (int wv = 1; wv < 4; ++wv) { ssum += red[0][wv][cg]; ssq += red[1][wv][cg]; }
      #pragma unroll
      for (int i = 0; i < 4; ++i) {
        atomicAdd(&sSum[col + i], ssum[i]);
        atomicAdd(&sSq[col + i], ssq[i]);
      }
    }
  }
}

// ---------------- BN (batch stats) + ELU + bf16 cast -------------------------
__global__ __launch_bounds__(256) void bnelu_kernel(
    const float* __restrict__ h, const float* __restrict__ sSum,
    const float* __restrict__ sSq, const float* __restrict__ gamma,
    const float* __restrict__ beta, u16* __restrict__ h1b)
{
  int idx = blockIdx.x * 256 + threadIdx.x;  // 131072 threads x 4 elems
  int col = (idx & 127) * 4;
  f32x4 hv = *(const f32x4*)(h + (size_t)idx * 4);
  u16x4 o;
  #pragma unroll
  for (int i = 0; i < 4; ++i) {
    int c = col + i;
    float mean = sSum[c] * (1.0f / 1024.0f);
    float var = sSq[c] * (1.0f / 1024.0f) - mean * mean;   // biased, matches ref
    float sc = gamma[c] * rsqrtf(var + 1e-5f);
    float hn = (hv[i] - mean) * sc + beta[c];
    float r = hn > 0.0f ? hn : expm1f(hn);                 // ELU(alpha=1)
    o[i] = f2bf(r);
  }
  *(u16x4*)(h1b + (size_t)idx * 4) = o;
}

extern "C" void kernel_launch(void* const* d_in, const int* in_sizes, int n_in,
                              void* d_out, int out_size, void* d_ws, size_t ws_size,
                              hipStream_t stream)
{
  const float* x     = (const float*)d_in[0];
  const float* coef  = (const float*)d_in[1];
  const float* w1    = (const float*)d_in[2];
  const float* b1    = (const float*)d_in[3];
  const float* w2    = (const float*)d_in[4];
  const float* b2    = (const float*)d_in[5];
  const float* gamma = (const float*)d_in[6];
  const float* beta  = (const float*)d_in[7];
  float* out = (float*)d_out;

  char* ws = (char*)d_ws;
  u16* w1t   = (u16*)(ws);                         //  4 MB  [8][512][512] bf16 (n,k)
  u16* w2t   = (u16*)(ws + (4u << 20));            //  4 MB
  u16* xb    = (u16*)(ws + (8u << 20));            //  1 MB  [1024][512] bf16
  u16* h1b   = (u16*)(ws + (9u << 20));            //  1 MB
  float* prt = (float*)(ws + (10u << 20));         // 16 MB  [8][1024][512] f32
  float* h   = (float*)(ws + (26u << 20));         //  2 MB  [1024][512] f32
  float* sS  = (float*)(ws + (28u << 20));         //  2 KB  col sums
  float* sQ  = (float*)(ws + (28u << 20) + 4096);  //  2 KB  col sumsq
  // total ws use: 28 MB + 8 KB

  hipMemsetAsync(sS, 0, 8192, stream);             // zero BN accumulators each call

  prep_kernel<<<1152, 256, 0, stream>>>(x, w1, w2, xb, w1t, w2t);
  gemm_expert<<<512, 256, 0, stream>>>(xb, w1t, prt);
  blend_kernel<1><<<128, 256, 0, stream>>>(prt, coef, b1, h, sS, sQ);
  bnelu_kernel<<<512, 256, 0, stream>>>(h, sS, sQ, gamma, beta, h1b);
  gemm_expert<<<512, 256, 0, stream>>>(h1b, w2t, prt);
  blend_kernel<0><<<128, 256, 0, stream>>>(prt, coef, b2, out, nullptr, nullptr);
}

// Round 2
// 63.406 us; speedup vs baseline: 1.0839x; 1.0839x over previous
//
#include <hip/hip_runtime.h>

// ExpertMLP: h = sum_e coef[b,e] * (x @ w1[e]) + coef@b1 ; BN(batch) ; ELU ;
//            out = sum_e coef[b,e] * (h1 @ w2[e]) + coef@b2
// B=1024, E=8, IN=HID=OUT=512. All fp32 in/out; compute in bf16 MFMA + f32 acc.
//
// R1 -> R2: removed the per-call hipMemsetAsync (graph-captured 8KB fill cost
// ~40us/replay per rocprof!). BN accumulators are now zeroed by an extra
// prep_kernel workgroup (stream-ordered before blend<1>'s atomics).

typedef short bf16x8 __attribute__((ext_vector_type(8)));
typedef float f32x4 __attribute__((ext_vector_type(4)));
typedef unsigned short u16;
typedef u16 u16x4 __attribute__((ext_vector_type(4)));

__device__ __forceinline__ u16 f2bf(float f) {
  union { float f; unsigned u; } v; v.f = f;
  return (u16)((v.u + 0x7FFFu + ((v.u >> 16) & 1u)) >> 16);  // RNE
}

#define AS_G(p) ((const __attribute__((address_space(1))) void*)(p))
#define AS_L(p) ((__attribute__((address_space(3))) void*)(p))

// ---------------- prep: x -> bf16 ; w1,w2 -> transposed bf16 [e][n][k];
//                  block 1152 zeroes the BN stat accumulators ---------------
__global__ __launch_bounds__(256) void prep_kernel(
    const float* __restrict__ x, const float* __restrict__ w1,
    const float* __restrict__ w2, u16* __restrict__ xb,
    u16* __restrict__ w1t, u16* __restrict__ w2t, float* __restrict__ stats)
{
  int bid = blockIdx.x, t = threadIdx.x;
  __shared__ float ld[64][65];   // padded to break bank conflicts on col reads
  if (bid >= 1152) {             // zero 8KB of BN accumulators (sS + sQ)
    f32x4 z = {0, 0, 0, 0};
    *(f32x4*)(stats + t * 8) = z;
    *(f32x4*)(stats + t * 8 + 4) = z;
    return;
  }
  if (bid < 128) {               // convert x: 128*256*16 = 524288 elems
    int p = (bid * 256 + t) * 16;
    #pragma unroll
    for (int i = 0; i < 4; ++i) {
      f32x4 v = *(const f32x4*)(x + p + i * 4);
      u16x4 o;
      o.x = f2bf(v.x); o.y = f2bf(v.y); o.z = f2bf(v.z); o.w = f2bf(v.w);
      *(u16x4*)(xb + p + i * 4) = o;
    }
    return;
  }
  int b2 = bid - 128;                        // 0..1023: 2 weights * 8 e * 64 tiles
  const float* src = (b2 >> 9) ? w2 : w1;
  u16* dst = (b2 >> 9) ? w2t : w1t;
  int rem = b2 & 511;
  int e = rem >> 6, tl = rem & 63;
  int kt = tl >> 3, nt = tl & 7;             // 64x64 tile at (kt,nt)
  #pragma unroll
  for (int j = 0; j < 4; ++j) {              // read [k][n] coalesced
    int kr = j * 16 + (t >> 4), nc = (t & 15) * 4;
    f32x4 v = *(const f32x4*)(src + (size_t)((e * 512 + kt * 64 + kr)) * 512 + nt * 64 + nc);
    ld[kr][nc] = v.x; ld[kr][nc + 1] = v.y; ld[kr][nc + 2] = v.z; ld[kr][nc + 3] = v.w;
  }
  __syncthreads();
  #pragma unroll
  for (int j = 0; j < 4; ++j) {              // write [n][k] coalesced, bf16
    int nr = j * 16 + (t >> 4), kc = (t & 15) * 4;
    u16x4 o;
    o.x = f2bf(ld[kc][nr]);     o.y = f2bf(ld[kc + 1][nr]);
    o.z = f2bf(ld[kc + 2][nr]); o.w = f2bf(ld[kc + 3][nr]);
    *(u16x4*)(dst + (size_t)((e * 512 + nt * 64 + nr)) * 512 + kt * 64 + kc) = o;
  }
}

// ---------------- per-expert GEMM: P[e] = A @ W[e]  (A:[1024][512] bf16,
//                  Wt:[8][512][512] bf16 stored [e][n][k]) ------------------
__global__ __launch_bounds__(256) void gemm_expert(
    const u16* __restrict__ A, const u16* __restrict__ Wt,
    float* __restrict__ P)
{
  // XCD swizzle: all 64 blocks of one expert land on one XCD (W panel L2-hot)
  int bid = (blockIdx.x & 7) * 64 + (blockIdx.x >> 3);   // 512 % 8 == 0, bijective
  int nt = bid & 7, mt = (bid >> 3) & 7, e = bid >> 6;
  int t = threadIdx.x, l = t & 63, w = t >> 6;
  int wm = w >> 1, wn = w & 1;                 // wave tile 64x32 of 128x64 block
  __shared__ alignas(16) u16 As[128 * 64];     // 16 KB, [row][k] linear
  __shared__ alignas(16) u16 Bs[64 * 64];      //  8 KB, [n][k] linear
  f32x4 acc[4][2] = {};
  const u16* Ag = A + (size_t)(mt * 128) * 512;
  const u16* Bg = Wt + (size_t)(e * 512 + nt * 64) * 512;
  int lr = l >> 3, lc = l & 7;                 // lane -> (row-in-8, 16B chunk)

  for (int kt = 0; kt < 8; ++kt) {
    int k0 = kt * 64;
    #pragma unroll
    for (int j = 0; j < 4; ++j) {              // stage A tile 128x64
      int row = j * 32 + w * 8;
      __builtin_amdgcn_global_load_lds(AS_G(Ag + (size_t)(row + lr) * 512 + k0 + lc * 8),
                                       AS_L(&As[row * 64]), 16, 0, 0);
    }
    #pragma unroll
    for (int j = 0; j < 2; ++j) {              // stage B tile 64x64
      int row = j * 32 + w * 8;
      __builtin_amdgcn_global_load_lds(AS_G(Bg + (size_t)(row + lr) * 512 + k0 + lc * 8),
                                       AS_L(&Bs[row * 64]), 16, 0, 0);
    }
    __syncthreads();                           // drains vmcnt before reads
    #pragma unroll
    for (int kk = 0; kk < 2; ++kk) {
      bf16x8 a[4], b[2];
      int ko = kk * 32 + (l >> 4) * 8;         // A/B frag: row=lane&15, k=8*(lane>>4)
      #pragma unroll
      for (int m = 0; m < 4; ++m)
        a[m] = *(const bf16x8*)&As[(wm * 64 + m * 16 + (l & 15)) * 64 + ko];
      #pragma unroll
      for (int n = 0; n < 2; ++n)
        b[n] = *(const bf16x8*)&Bs[(wn * 32 + n * 16 + (l & 15)) * 64 + ko];
      #pragma unroll
      for (int m = 0; m < 4; ++m)
        #pragma unroll
        for (int n = 0; n < 2; ++n)
          acc[m][n] = __builtin_amdgcn_mfma_f32_16x16x32_bf16(a[m], b[n], acc[m][n], 0, 0, 0);
    }
    __syncthreads();                           // LDS reads done before restage
  }
  // epilogue: C/D layout col=lane&15, row=(lane>>4)*4+reg (guide-verified)
  float* Pe = P + (size_t)((e << 10) + mt * 128 + wm * 64) * 512 + nt * 64 + wn * 32;
  #pragma unroll
  for (int m = 0; m < 4; ++m)
    #pragma unroll
    for (int n = 0; n < 2; ++n) {
      int col = n * 16 + (l & 15);
      int rbase = m * 16 + (l >> 4) * 4;
      #pragma unroll
      for (int r = 0; r < 4; ++r)
        Pe[(size_t)(rbase + r) * 512 + col] = acc[m][n][r];
    }
}

// ---------------- blend-reduce: out = sum_e coef*(P[e]+bias[e]); opt BN stats --
template <int STATS>
__global__ __launch_bounds__(256) void blend_kernel(
    const float* __restrict__ P, const float* __restrict__ coef,
    const float* __restrict__ bias, float* __restrict__ out,
    float* __restrict__ sSum, float* __restrict__ sSq)
{
  int bid = blockIdx.x;                      // 128 blocks: 64 row-blks x 2 col-blks
  int mblk = bid >> 1, cblk = bid & 1;
  int t = threadIdx.x, w = t >> 6, cg = t & 63;
  int col = cblk * 256 + cg * 4;
  f32x4 ssum = {0, 0, 0, 0}, ssq = {0, 0, 0, 0};
  #pragma unroll
  for (int rj = 0; rj < 4; ++rj) {
    int row = mblk * 16 + rj * 4 + w;
    const float* cr = coef + row * 8;
    f32x4 acc = {0, 0, 0, 0};
    #pragma unroll
    for (int e = 0; e < 8; ++e) {
      float c = cr[e];
      f32x4 p = *(const f32x4*)(P + (size_t)((e << 10) + row) * 512 + col);
      f32x4 bb = *(const f32x4*)(bias + e * 512 + col);
      acc += c * (p + bb);
    }
    *(f32x4*)(out + (size_t)row * 512 + col) = acc;
    if constexpr (STATS) { ssum += acc; ssq += acc * acc; }
  }
  if constexpr (STATS) {
    __shared__ f32x4 red[2][4][64];
    red[0][w][cg] = ssum; red[1][w][cg] = ssq;
    __syncthreads();
    if (w == 0) {
      #pragma unroll
      for (int wv = 1; wv < 4; ++wv) { ssum += red[0][wv][cg]; ssq += red[1][wv][cg]; }
      #pragma unroll
      for (int i = 0; i < 4; ++i) {
        atomicAdd(&sSum[col + i], ssum[i]);
        atomicAdd(&sSq[col + i], ssq[i]);
      }
    }
  }
}

// ---------------- BN (batch stats) + ELU + bf16 cast -------------------------
__global__ __launch_bounds__(256) void bnelu_kernel(
    const float* __restrict__ h, const float* __restrict__ sSum,
    const float* __restrict__ sSq, const float* __restrict__ gamma,
    const float* __restrict__ beta, u16* __restrict__ h1b)
{
  int idx = blockIdx.x * 256 + threadIdx.x;  // 131072 threads x 4 elems
  int col = (idx & 127) * 4;
  f32x4 hv = *(const f32x4*)(h + (size_t)idx * 4);
  u16x4 o;
  #pragma unroll
  for (int i = 0; i < 4; ++i) {
    int c = col + i;
    float mean = sSum[c] * (1.0f / 1024.0f);
    float var = sSq[c] * (1.0f / 1024.0f) - mean * mean;   // biased, matches ref
    float sc = gamma[c] * rsqrtf(var + 1e-5f);
    float hn = (hv[i] - mean) * sc + beta[c];
    float r = hn > 0.0f ? hn : expm1f(hn);                 // ELU(alpha=1)
    o[i] = f2bf(r);
  }
  *(u16x4*)(h1b + (size_t)idx * 4) = o;
}

extern "C" void kernel_launch(void* const* d_in, const int* in_sizes, int n_in,
                              void* d_out, int out_size, void* d_ws, size_t ws_size,
                              hipStream_t stream)
{
  const float* x     = (const float*)d_in[0];
  const float* coef  = (const float*)d_in[1];
  const float* w1    = (const float*)d_in[2];
  const float* b1    = (const float*)d_in[3];
  const float* w2    = (const float*)d_in[4];
  const float* b2    = (const float*)d_in[5];
  const float* gamma = (const float*)d_in[6];
  const float* beta  = (const float*)d_in[7];
  float* out = (float*)d_out;

  char* ws = (char*)d_ws;
  u16* w1t   = (u16*)(ws);                         //  4 MB  [8][512][512] bf16 (n,k)
  u16* w2t   = (u16*)(ws + (4u << 20));            //  4 MB
  u16* xb    = (u16*)(ws + (8u << 20));            //  1 MB  [1024][512] bf16
  u16* h1b   = (u16*)(ws + (9u << 20));            //  1 MB
  float* prt = (float*)(ws + (10u << 20));         // 16 MB  [8][1024][512] f32
  float* h   = (float*)(ws + (26u << 20));         //  2 MB  [1024][512] f32
  float* sS  = (float*)(ws + (28u << 20));         //  2 KB  col sums
  float* sQ  = (float*)(ws + (28u << 20) + 4096);  //  2 KB  col sumsq
  // total ws use: 28 MB + 8 KB

  prep_kernel<<<1153, 256, 0, stream>>>(x, w1, w2, xb, w1t, w2t, sS);
  gemm_expert<<<512, 256, 0, stream>>>(xb, w1t, prt);
  blend_kernel<1><<<128, 256, 0, stream>>>(prt, coef, b1, h, sS, sQ);
  bnelu_kernel<<<512, 256, 0, stream>>>(h, sS, sQ, gamma, beta, h1b);
  gemm_expert<<<512, 256, 0, stream>>>(h1b, w2t, prt);
  blend_kernel<0><<<128, 256, 0, stream>>>(prt, coef, b2, out, nullptr, nullptr);
}